// Round 11
// baseline (432.510 us; speedup 1.0000x reference)
//
#include <hip/hip_runtime.h>
#include <hip/hip_bf16.h>

typedef __attribute__((ext_vector_type(8))) __bf16 bf16x8;
typedef __attribute__((ext_vector_type(4))) __bf16 bf16x4;
typedef __attribute__((ext_vector_type(4))) float f32x4;

#define MFMA16(a, b, c) __builtin_amdgcn_mfma_f32_16x16x32_bf16((a), (b), (c), 0, 0, 0)

__device__ __forceinline__ void gload_lds16(const void* g, void* l) {
    __builtin_amdgcn_global_load_lds((const __attribute__((address_space(1))) void*)g,
                                     (__attribute__((address_space(3))) void*)l, 16, 0, 0);
}

// XOR-swizzle within each 1KB (16-row) region of a [R][32]bf16 LDS tile (64B rows).
// byte' = byte ^ (((byte>>7)&7)<<4). Involution; write via pre-swizzled global source.
__device__ __forceinline__ int lds_swz(int r, int ck) {
    int W = ((r & 15) << 6) | (ck << 4);
    W ^= ((W >> 7) & 7) << 4;
    return ((r >> 4) << 9) + (W >> 1);
}

// ---------------- f32 -> bf16 convert (x) ----------------
__global__ __launch_bounds__(256) void cvt_bf16(const float* __restrict__ in,
                                                __bf16* __restrict__ out, int n4) {
    int i = blockIdx.x * 256 + threadIdx.x;
    if (i >= n4) return;
    f32x4 v = *(const f32x4*)(in + (size_t)i * 4);
    bf16x4 o;
#pragma unroll
    for (int j = 0; j < 4; j++) o[j] = (__bf16)v[j];
    *(bf16x4*)(out + (size_t)i * 4) = o;
}

// ---------------- weight transpose f32 (R,C) -> bf16 (C,R) ----------------
__global__ __launch_bounds__(256) void transpose_w(const float* __restrict__ in,
                                                   __bf16* __restrict__ out, int R, int C) {
    __shared__ float tile[32][33];
    const int c0 = blockIdx.x * 32, r0 = blockIdx.y * 32;
    const int tx = threadIdx.x, ty = threadIdx.y;
#pragma unroll
    for (int k = 0; k < 32; k += 8)
        tile[ty + k][tx] = in[(size_t)(r0 + ty + k) * C + c0 + tx];
    __syncthreads();
#pragma unroll
    for (int k = 0; k < 32; k += 8)
        out[(size_t)(c0 + ty + k) * R + r0 + tx] = (__bf16)tile[tx][ty + k];
}

// ---------------- GEMM: C(M,N) = A(M,K)bf16 @ Bt(N,K)bf16^T ----------------
// 256x256 tile, 8 waves (2M x 4N, 128x64 per wave), 3-buffer LDS, prefetch-ahead-2,
// counted vmcnt(4), raw s_barrier, XOR-swizzled tiles. M,N divisible by 256.
template <typename OUT_T>
__global__ __launch_bounds__(512, 1) void gemm_bt(const __bf16* __restrict__ A,
                                                  const __bf16* __restrict__ Bt,
                                                  OUT_T* __restrict__ C, int M, int N, int K) {
    __shared__ alignas(16) __bf16 As[3][8192];  // [256][32] each
    __shared__ alignas(16) __bf16 Bs[3][8192];
    const int tid = threadIdx.x;
    const int wv = tid >> 6;
    const int l = tid & 63;
    const int nwg = gridDim.x;
    const int cpx = nwg >> 3;
    const int bid = blockIdx.x;
    const int wg = (bid & 7) * cpx + (bid >> 3);  // XCD swizzle (nwg % 8 == 0)
    const int nbn = N >> 8;
    const int bm = wg / nbn, bn = wg - bm * nbn;

    const __bf16* Ab = A + (size_t)bm * 256 * K;
    const __bf16* Bb = Bt + (size_t)bn * 256 * K;
    // pre-swizzled global source for the linear global_load_lds dest (slot byte = l*16)
    const int L = (l << 4) ^ ((l >> 3) << 4);
    const int sr = L >> 6;               // swizzled row-in-region 0..15
    const int sc8 = ((L >> 4) & 3) * 8;  // swizzled 16B-chunk -> element offset
    const int lr = l & 15;
    const int ck = l >> 4;               // 0..3
    const int wm = (wv >> 2) * 128, wn = (wv & 3) * 64;

    auto STAGE = [&](int buf, int kt) {
        gload_lds16(Ab + (size_t)(wv * 32 + sr) * K + kt + sc8, &As[buf][0] + wv * 1024);
        gload_lds16(Ab + (size_t)(wv * 32 + 16 + sr) * K + kt + sc8, &As[buf][0] + wv * 1024 + 512);
        gload_lds16(Bb + (size_t)(wv * 32 + sr) * K + kt + sc8, &Bs[buf][0] + wv * 1024);
        gload_lds16(Bb + (size_t)(wv * 32 + 16 + sr) * K + kt + sc8, &Bs[buf][0] + wv * 1024 + 512);
    };

    const int nt = K >> 5;  // K >= 1024 here, nt >= 32
    STAGE(0, 0);
    STAGE(1, 32);

    f32x4 acc[8][4] = {};
    int buf = 0;
    for (int t = 0; t < nt; ++t) {
        asm volatile("s_waitcnt lgkmcnt(0)" ::: "memory");
        if (t + 1 < nt)
            asm volatile("s_waitcnt vmcnt(4)" ::: "memory");  // tile t done; t+1 in flight
        else
            asm volatile("s_waitcnt vmcnt(0)" ::: "memory");
        __builtin_amdgcn_s_barrier();
        __builtin_amdgcn_sched_barrier(0);
        if (t + 2 < nt) {
            int nb = buf + 2;
            if (nb >= 3) nb -= 3;
            STAGE(nb, (t + 2) * 32);
        }
        const __bf16* as = &As[buf][0];
        const __bf16* bs = &Bs[buf][0];
        bf16x8 af[8], bfr[4];
#pragma unroll
        for (int i = 0; i < 8; i++) af[i] = *(const bf16x8*)(as + lds_swz(wm + i * 16 + lr, ck));
#pragma unroll
        for (int j = 0; j < 4; j++) bfr[j] = *(const bf16x8*)(bs + lds_swz(wn + j * 16 + lr, ck));
#pragma unroll
        for (int i = 0; i < 8; i++)
#pragma unroll
            for (int j = 0; j < 4; j++) acc[i][j] = MFMA16(af[i], bfr[j], acc[i][j]);
        buf += 1;
        if (buf >= 3) buf -= 3;
    }
    const int lro = ck * 4;
#pragma unroll
    for (int i = 0; i < 8; i++)
#pragma unroll
        for (int j = 0; j < 4; j++) {
            size_t base = (size_t)(bm * 256 + wm + i * 16 + lro) * N + bn * 256 + wn + j * 16 + lr;
#pragma unroll
            for (int r = 0; r < 4; r++) C[base + (size_t)r * N] = (OUT_T)acc[i][j][r];
        }
}

// ---------------- t = x @ gk_w1  (8192x16) ----------------
__global__ __launch_bounds__(256) void gk1_proj(const float* __restrict__ x,
                                                const float* __restrict__ w1,
                                                float* __restrict__ t) {
    const int row = blockIdx.x * 4 + (threadIdx.x >> 6);
    const int l = threadIdx.x & 63;
    const int r = l & 15, kg = l >> 4;
    const float* xr = x + (size_t)row * 1024;
    const float* w1p = w1 + r;
    float acc = 0.f;
    for (int k = kg * 256; k < (kg + 1) * 256; ++k) acc = fmaf(xr[k], w1p[k * 16], acc);
    acc += __shfl_xor(acc, 16);
    acc += __shfl_xor(acc, 32);
    if (kg == 0) t[(size_t)row * 16 + r] = acc;
}

// ---------------- per-(b,h,chunk128): gates, qg, kg, kgT, e^blast ----------------
// block 1024 = 4 c-quarters x 256 d. Serial chain is 32 (not 128); quarter prefix via LDS.
__global__ __launch_bounds__(1024, 4) void gate_qkg(
    const float* __restrict__ tbuf,   // (8192,16)
    const float* __restrict__ w2,     // (16,1024)
    const float* __restrict__ b2,     // (1024)
    const __bf16* __restrict__ qkbuf, // (8192,2048): q|k
    __bf16* __restrict__ qg,          // (8192,1024)
    __bf16* __restrict__ kg,          // (8192,1024)
    __bf16* __restrict__ kgT,         // (16,256,2048) [bh][d][seq]
    float* __restrict__ ebl)          // (16,16,256) [nc][bh][d]
{
    __shared__ alignas(16) float t_l[128 * 16];  // 8KB
    __shared__ float qs[4 * 256];                // 4KB quarter totals
    __shared__ __bf16 kg_l[128 * 260];           // 66.5KB
    const int bid = blockIdx.x;
    const int bh = bid & 15, nc = bid >> 4;
    const int b = bh >> 2, h = bh & 3;
    const int tid = threadIdx.x;
    const int d = tid & 255, cq = tid >> 8;
    const int seq0 = b * 2048 + nc * 128;
    const int hd = h * 256 + d;

    for (int i = tid; i < 128 * 16; i += 1024) t_l[i] = tbuf[(size_t)seq0 * 16 + i];
    float w2c[16];
#pragma unroll
    for (int r = 0; r < 16; r++) w2c[r] = w2[r * 1024 + hd];
    const float b2v = b2[hd];
    __syncthreads();

    // phase B: within-quarter inclusive cumsum of log-sigmoid gates (registers, unrolled)
    float bs[32];
    float run = 0.f;
#pragma unroll
    for (int j = 0; j < 32; j++) {
        const int c = cq * 32 + j;
        f32x4 t0 = *(const f32x4*)(t_l + c * 16);
        f32x4 t1 = *(const f32x4*)(t_l + c * 16 + 4);
        f32x4 t2 = *(const f32x4*)(t_l + c * 16 + 8);
        f32x4 t3 = *(const f32x4*)(t_l + c * 16 + 12);
        float u = b2v;
#pragma unroll
        for (int r = 0; r < 4; r++) {
            u = fmaf(t0[r], w2c[r], u);
            u = fmaf(t1[r], w2c[4 + r], u);
            u = fmaf(t2[r], w2c[8 + r], u);
            u = fmaf(t3[r], w2c[12 + r], u);
        }
        const float ls = fminf(u, 0.f) - __logf(1.f + __expf(-fabsf(u)));
        run += ls * 0.0625f;  // / GATE_NORM
        bs[j] = run;
    }
    qs[cq * 256 + d] = run;
    __syncthreads();

    float prefix = 0.f;
#pragma unroll
    for (int q = 0; q < 3; q++)
        if (q < cq) prefix += qs[q * 256 + d];

    // phase C: apply gates to q/k, write qg/kg, stage kg for transpose
#pragma unroll
    for (int j = 0; j < 32; j++) {
        const int c = cq * 32 + j;
        const float bsum = prefix + bs[j];
        const float eb = __expf(bsum);
        const float en = __expf(-bsum);
        const float qv = (float)qkbuf[(size_t)(seq0 + c) * 2048 + hd];
        const float kv = (float)qkbuf[(size_t)(seq0 + c) * 2048 + 1024 + hd];
        qg[(size_t)(seq0 + c) * 1024 + hd] = (__bf16)(qv * eb * 0.0625f);
        const __bf16 kgv = (__bf16)(kv * en);
        kg[(size_t)(seq0 + c) * 1024 + hd] = kgv;
        kg_l[c * 260 + d] = kgv;
    }
    if (cq == 3) ebl[(size_t)(nc * 16 + bh) * 256 + d] = __expf(prefix + bs[31]);
    __syncthreads();

    // phase D: transpose kg -> kgT (seq-contiguous rows per d); 1024 threads, 32 iters each
    {
        const int cc = tid & 127, dgroup = tid >> 7;  // 8 groups of 32 d
        for (int i = 0; i < 32; i++) {
            const int dd = dgroup * 32 + i;
            kgT[(size_t)(bh * 256 + dd) * 2048 + nc * 128 + cc] = kg_l[cc * 260 + dd];
        }
    }
}

// ---------------- a_mat: A = causal(qg kg^T), materialized (256 pairs) ----------------
// grid 256 = pair (nc*16+bh), block 512 (8 waves).
// A is 128x128: 8x8 grid of 16x16 blocks; 36 lower-triangle blocks dealt round-robin to 8 waves.
__global__ __launch_bounds__(512) void a_mat(
    const __bf16* __restrict__ qg, const __bf16* __restrict__ kg,
    __bf16* __restrict__ Abuf) {
    const int pair = blockIdx.x;
    const int bh = pair & 15, nc = pair >> 4;
    const int b = bh >> 2, h = bh & 3;
    const int tid = threadIdx.x, wv = tid >> 6, l = tid & 63;
    const int lr = l & 15, lk = (l >> 4) * 8, lro = (l >> 4) * 4;
    const int seq0 = b * 2048 + nc * 128;
    __bf16* Ab = Abuf + (size_t)pair * 16384;

    // phase 1: zero the whole 128x128 tile
    {
        bf16x8 z = {};
        for (int i = tid; i < 2048; i += 512) *(bf16x8*)(Ab + (size_t)i * 8) = z;
    }
    __syncthreads();

    // phase 2: compute lower-triangle 16x16 blocks (j = t-strip, s = s-strip, s <= j)
    static const int TJ[36] = {0,1,1,2,2,2,3,3,3,3,4,4,4,4,4,5,5,5,5,5,5,
                               6,6,6,6,6,6,6,7,7,7,7,7,7,7,7};
    static const int TS[36] = {0,0,1,0,1,2,0,1,2,3,0,1,2,3,4,0,1,2,3,4,5,
                               0,1,2,3,4,5,6,0,1,2,3,4,5,6,7};
    for (int m = wv; m < 36; m += 8) {
        const int j = TJ[m], s = TS[m];
        f32x4 acc = {};
        const __bf16* qrow = qg + (size_t)(seq0 + j * 16 + lr) * 1024 + h * 256;
        const __bf16* krow = kg + (size_t)(seq0 + s * 16 + lr) * 1024 + h * 256;
#pragma unroll
        for (int ks = 0; ks < 8; ks++) {
            bf16x8 a = *(const bf16x8*)(qrow + ks * 32 + lk);
            bf16x8 bb = *(const bf16x8*)(krow + ks * 32 + lk);
            acc = MFMA16(a, bb, acc);
        }
#pragma unroll
        for (int r = 0; r < 4; r++) {
            const int t = j * 16 + lro + r;
            const int ss = s * 16 + lr;
            if (ss <= t) Ab[t * 128 + ss] = (__bf16)acc[r];
        }
    }
}

// ---------------- ointer: o = [A|qg] @ [vt_slice | H_slot]^T ----------------
// grid 1024 = pair(256) x bn(4), block 256. K = 384 (128 s + 256 d); nc==0 -> K=128.
// Pipelined + swizzled 128-tile structure (4 waves).
__global__ __launch_bounds__(256) void ointer(
    const __bf16* __restrict__ Abuf, const __bf16* __restrict__ qg,
    const __bf16* __restrict__ vt, const __bf16* __restrict__ UH,
    __bf16* __restrict__ ob) {
    __shared__ alignas(16) __bf16 As[3][4096];
    __shared__ alignas(16) __bf16 Bs[3][4096];
    const int tid = threadIdx.x;
    const int wv = tid >> 6;
    const int l = tid & 63;
    const int bid = blockIdx.x;
    const int wg = (bid & 7) * 128 + (bid >> 3);  // XCD swizzle, 1024 blocks
    const int bn = wg & 3, pair = wg >> 2;        // consecutive wg share pair -> L2 reuse of A/qg
    const int bh = pair & 15, nc = pair >> 4;
    const int b = bh >> 2, h = bh & 3;
    const int seq0 = b * 2048 + nc * 128;
    const int L = (l << 4) ^ ((l >> 3) << 4);
    const int sr = L >> 6;
    const int sc8 = ((L >> 4) & 3) * 8;
    const int lr = tid & 15;
    const int ck = (tid >> 4) & 3;
    const int wm = (wv >> 1) * 64, wn = (wv & 1) * 64;
    const int KE = (nc == 0) ? 128 : 384;

    const __bf16* Ap = Abuf + (size_t)pair * 16384;
    const __bf16* Hb = UH + ((size_t)((nc - 1) * 16 + bh) * 512 + bn * 128) * 256;

    auto STAGE = [&](int buf, int kt) {
        const __bf16 *a0, *a1, *b0, *b1;
        if (kt < 128) {
            a0 = Ap + (size_t)(wv * 16 + sr) * 128 + kt + sc8;
            a1 = Ap + (size_t)(64 + wv * 16 + sr) * 128 + kt + sc8;
            b0 = vt + (size_t)(h * 512 + bn * 128 + wv * 16 + sr) * 8192 + seq0 + kt + sc8;
            b1 = vt + (size_t)(h * 512 + bn * 128 + 64 + wv * 16 + sr) * 8192 + seq0 + kt + sc8;
        } else {
            const int kd = kt - 128;
            a0 = qg + (size_t)(seq0 + wv * 16 + sr) * 1024 + h * 256 + kd + sc8;
            a1 = qg + (size_t)(seq0 + 64 + wv * 16 + sr) * 1024 + h * 256 + kd + sc8;
            b0 = Hb + (size_t)(wv * 16 + sr) * 256 + kd + sc8;
            b1 = Hb + (size_t)(64 + wv * 16 + sr) * 256 + kd + sc8;
        }
        gload_lds16(a0, &As[buf][0] + wv * 512);
        gload_lds16(a1, &As[buf][0] + 2048 + wv * 512);
        gload_lds16(b0, &Bs[buf][0] + wv * 512);
        gload_lds16(b1, &Bs[buf][0] + 2048 + wv * 512);
    };

    const int nt = KE >> 5;  // 4 or 12
    STAGE(0, 0);
    STAGE(1, 32);

    f32x4 acc[4][4] = {};
    int buf = 0;
    for (int t = 0; t < nt; ++t) {
        asm volatile("s_waitcnt lgkmcnt(0)" ::: "memory");
        if (t + 1 < nt)
            asm volatile("s_waitcnt vmcnt(4)" ::: "memory");
        else
            asm volatile("s_waitcnt vmcnt(0)" ::: "memory");
        __builtin_amdgcn_s_barrier();
        __builtin_amdgcn_sched_barrier(0);
        if (t + 2 < nt) {
            int nb = buf + 2;
            if (nb >= 3) nb -= 3;
            STAGE(nb, (t + 2) * 32);
        }
        const __bf16* as = &As[buf][0];
        const __bf16* bs = &Bs[buf][0];
        bf16x8 af[4], bfr[4];
#pragma unroll
        for (int i = 0; i < 4; i++) af[i] = *(const bf16x8*)(as + lds_swz(wm + i * 16 + lr, ck));
#pragma unroll
        for (int j = 0; j < 4; j++) bfr[j] = *(const bf16x8*)(bs + lds_swz(wn + j * 16 + lr, ck));
#pragma unroll
        for (int i = 0; i < 4; i++)
#pragma unroll
            for (int j = 0; j < 4; j++) acc[i][j] = MFMA16(af[i], bfr[j], acc[i][j]);
        buf += 1;
        if (buf >= 3) buf -= 3;
    }
    const int lro = ((tid >> 4) & 3) * 4;
#pragma unroll
    for (int i = 0; i < 4; i++)
#pragma unroll
        for (int j = 0; j < 4; j++) {
            size_t base = (size_t)(seq0 + wm + i * 16 + lro) * 2048 + h * 512 + bn * 128 + wn + j * 16 + lr;
#pragma unroll
            for (int r = 0; r < 4; r++) ob[base + (size_t)r * 2048] = (__bf16)acc[i][j][r];
        }
}

// ---------------- chunk_u: Ut_i[e][d] = sum_c vt[e][c] * kgT[d][c]  (parallel over all chunks) ----
// grid 1024 = q(4: eh*2+dh) x nc(16) x bh(16), block 512 (8 waves: 4 e-frags x 2 d-frags)
__global__ __launch_bounds__(512) void chunk_u(
    const __bf16* __restrict__ vt, const __bf16* __restrict__ kgT,
    __bf16* __restrict__ UH) {
    const int bid = blockIdx.x;
    const int bh = bid & 15, nc = (bid >> 4) & 15, q = bid >> 8;
    const int eh = q >> 1, dh = q & 1;
    const int b = bh >> 2, h = bh & 3;
    const int tid = threadIdx.x, wv = tid >> 6, l = tid & 63;
    const int lr = l & 15, lk = (l >> 4) * 8, lro = (l >> 4) * 4;
    const int seq0 = b * 2048 + nc * 128;
    const int e0 = eh * 256 + (wv >> 1) * 64;  // within [0,512)
    const int d0 = dh * 128 + (wv & 1) * 64;   // within [0,256)
    const __bf16* va = vt + (size_t)(h * 512 + e0) * 8192 + seq0;
    const __bf16* kb = kgT + (size_t)(bh * 256 + d0) * 2048 + nc * 128;

    f32x4 acc[4][4] = {};
#pragma unroll
    for (int ks = 0; ks < 4; ks++) {
        bf16x8 af[4], bf_[4];
#pragma unroll
        for (int i = 0; i < 4; i++)
            af[i] = *(const bf16x8*)(va + (size_t)(i * 16 + lr) * 8192 + ks * 32 + lk);
#pragma unroll
        for (int j = 0; j < 4; j++)
            bf_[j] = *(const bf16x8*)(kb + (size_t)(j * 16 + lr) * 2048 + ks * 32 + lk);
#pragma unroll
        for (int i = 0; i < 4; i++)
#pragma unroll
            for (int j = 0; j < 4; j++) acc[i][j] = MFMA16(af[i], bf_[j], acc[i][j]);
    }
    __bf16* ub = UH + ((size_t)(nc * 16 + bh) * 512 + e0) * 256 + d0;
#pragma unroll
    for (int i = 0; i < 4; i++)
#pragma unroll
        for (int j = 0; j < 4; j++)
#pragma unroll
            for (int r = 0; r < 4; r++)
                ub[(size_t)(i * 16 + lro + r) * 256 + j * 16 + lr] = (__bf16)acc[i][j][r];
}

// ---------------- hscan: in-place elementwise scan over 16 chunk slots ----------------
// slot i holds Ut_i on entry; on exit holds H_{i+1} = E_i (H_i + Ut_i).  H in f32 regs.
__global__ __launch_bounds__(256) void hscan(__bf16* __restrict__ UH,
                                             const float* __restrict__ ebl) {
    const int t = blockIdx.x * 256 + threadIdx.x;  // 262144 threads
    const int bh = t >> 14;
    const int rem = t & 16383;
    const int e = rem >> 5, d0 = (rem & 31) * 8;
    float H[8];
#pragma unroll
    for (int j = 0; j < 8; j++) H[j] = 0.f;
    for (int i = 0; i < 16; i++) {
        size_t idx = ((size_t)(i * 16 + bh) * 512 + e) * 256 + d0;
        bf16x8 u = *(const bf16x8*)(UH + idx);
        const float* ep = ebl + (size_t)(i * 16 + bh) * 256 + d0;
        f32x4 e0v = *(const f32x4*)ep;
        f32x4 e1v = *(const f32x4*)(ep + 4);
        bf16x8 hw;
#pragma unroll
        for (int j = 0; j < 4; j++) {
            H[j] = e0v[j] * (H[j] + (float)u[j]);
            hw[j] = (__bf16)H[j];
        }
#pragma unroll
        for (int j = 4; j < 8; j++) {
            H[j] = e1v[j - 4] * (H[j] + (float)u[j]);
            hw[j] = (__bf16)H[j];
        }
        *(bf16x8*)(UH + idx) = hw;
    }
}

// ---------------- RMS norm over dv=512 + SiLU gating ----------------
__global__ __launch_bounds__(256) void rms_gate(const __bf16* __restrict__ ob,
                                                const __bf16* __restrict__ gbuf,
                                                const float* __restrict__ gnw,
                                                __bf16* __restrict__ gated) {
    const int idx = blockIdx.x * 4 + (threadIdx.x >> 6);
    const int seq = idx >> 2, h = idx & 3;
    const int l = threadIdx.x & 63;
    bf16x8 o1 = *(const bf16x8*)(ob + (size_t)seq * 2048 + h * 512 + l * 8);
    float v[8];
    float ms = 0.f;
#pragma unroll
    for (int j = 0; j < 8; j++) {
        v[j] = (float)o1[j];
        ms += v[j] * v[j];
    }
#pragma unroll
    for (int off = 1; off < 64; off <<= 1) ms += __shfl_xor(ms, off);
    const float rinv = rsqrtf(ms * (1.f / 512.f) + 1e-5f);
    bf16x8 gv = *(const bf16x8*)(gbuf + (size_t)seq * 2048 + h * 512 + l * 8);
    const float* gw = gnw + l * 8;
    bf16x8 outv;
#pragma unroll
    for (int j = 0; j < 8; j++) {
        float g = (float)gv[j];
        float sig = 1.f / (1.f + expf(-g));
        outv[j] = (__bf16)(v[j] * rinv * gw[j] * g * sig);
    }
    *(bf16x8*)(gated + (size_t)seq * 2048 + h * 512 + l * 8) = outv;
}

extern "C" void kernel_launch(void* const* d_in, const int* in_sizes, int n_in,
                              void* d_out, int out_size, void* d_ws, size_t ws_size,
                              hipStream_t stream) {
    const float* x = (const float*)d_in[0];
    const float* Wq = (const float*)d_in[1];
    const float* Wk = (const float*)d_in[2];
    const float* Wv = (const float*)d_in[3];
    const float* Wg = (const float*)d_in[4];
    const float* w1 = (const float*)d_in[5];
    const float* w2 = (const float*)d_in[6];
    const float* b2 = (const float*)d_in[7];
    const float* gnw = (const float*)d_in[8];
    const float* Wo = (const float*)d_in[9];
    float* out = (float*)d_out;

    char* p = (char*)d_ws;
    auto nxt = [&](size_t bytes) {
        char* r = p;
        p += (bytes + 255) & ~(size_t)255;
        return r;
    };
    __bf16* xb = (__bf16*)nxt(8192ull * 1024 * 2);    // dead after vt GEMM -> kg aliases
    __bf16* WTqk = (__bf16*)nxt(2048ull * 1024 * 2);  // WqT | WkT; dead after proj -> Abuf aliases
    __bf16* WTg = (__bf16*)nxt(2048ull * 1024 * 2);   // dead after proj -> Abuf aliases
    __bf16* WvT = (__bf16*)nxt(2048ull * 1024 * 2);   // dead after proj
    __bf16* WoT = (__bf16*)nxt(1024ull * 2048 * 2);   // live until final GEMM
    __bf16* gbuf = (__bf16*)nxt(8192ull * 2048 * 2);
    __bf16* vt = (__bf16*)nxt(2048ull * 8192 * 2);
    float* tbuf = (float*)nxt(8192ull * 16 * 4);
    __bf16* qg = (__bf16*)nxt(8192ull * 1024 * 2);
    __bf16* kgT = (__bf16*)nxt(16ull * 256 * 2048 * 2);
    float* ebl = (float*)nxt(16ull * 16 * 256 * 4);
    __bf16* ob = (__bf16*)nxt(8192ull * 2048 * 2);
    __bf16* UH = (__bf16*)nxt(16ull * 16 * 512 * 256 * 2);  // 64MB: Ut slots -> H states (in-place)
    __bf16* kg = xb;        // alias: xb dead before gate_qkg writes kg
    __bf16* qkbuf = UH;     // alias: q|k projection; dead (read by gate_qkg) before chunk_u writes UH
    __bf16* gated = UH;     // alias: UH dead (read by ointer) before rms_gate writes gated
    __bf16* Abuf = WTqk;    // alias: 8MB = WTqk+WTg exactly, both dead before a_mat

    dim3 tb(32, 8);
    cvt_bf16<<<8192, 256, 0, stream>>>(x, xb, 2097152);
    transpose_w<<<dim3(32, 32), tb, 0, stream>>>(Wq, WTqk, 1024, 1024);
    transpose_w<<<dim3(32, 32), tb, 0, stream>>>(Wk, WTqk + 1024 * 1024, 1024, 1024);
    transpose_w<<<dim3(64, 32), tb, 0, stream>>>(Wg, WTg, 1024, 2048);
    transpose_w<<<dim3(64, 32), tb, 0, stream>>>(Wv, WvT, 1024, 2048);
    transpose_w<<<dim3(32, 64), tb, 0, stream>>>(Wo, WoT, 2048, 1024);
    gk1_proj<<<2048, 256, 0, stream>>>(x, w1, tbuf);
    gemm_bt<__bf16><<<256, 512, 0, stream>>>(xb, WTqk, qkbuf, 8192, 2048, 1024);
    gemm_bt<__bf16><<<256, 512, 0, stream>>>(xb, WTg, gbuf, 8192, 2048, 1024);
    gemm_bt<__bf16><<<256, 512, 0, stream>>>(WvT, xb, vt, 2048, 8192, 1024);
    gate_qkg<<<256, 1024, 0, stream>>>(tbuf, w2, b2, qkbuf, qg, kg, kgT, ebl);
    a_mat<<<256, 512, 0, stream>>>(qg, kg, Abuf);
    chunk_u<<<1024, 512, 0, stream>>>(vt, kgT, UH);
    hscan<<<1024, 256, 0, stream>>>(UH, ebl);
    ointer<<<1024, 256, 0, stream>>>(Abuf, qg, vt, UH, ob);
    rms_gate<<<8192, 256, 0, stream>>>(ob, gbuf, gnw, gated);
    gemm_bt<float><<<128, 512, 0, stream>>>(gated, WoT, out, 8192, 1024, 2048);
}

// Round 12
// 411.163 us; speedup vs baseline: 1.0519x; 1.0519x over previous
//
#include <hip/hip_runtime.h>
#include <hip/hip_bf16.h>

typedef __attribute__((ext_vector_type(8))) __bf16 bf16x8;
typedef __attribute__((ext_vector_type(4))) __bf16 bf16x4;
typedef __attribute__((ext_vector_type(4))) float f32x4;

#define MFMA16(a, b, c) __builtin_amdgcn_mfma_f32_16x16x32_bf16((a), (b), (c), 0, 0, 0)

__device__ __forceinline__ void gload_lds16(const void* g, void* l) {
    __builtin_amdgcn_global_load_lds((const __attribute__((address_space(1))) void*)g,
                                     (__attribute__((address_space(3))) void*)l, 16, 0, 0);
}

// XOR-swizzle within each 1KB (16-row) region of a [R][32]bf16 LDS tile (64B rows).
// byte' = byte ^ (((byte>>7)&7)<<4). Involution; write via pre-swizzled global source.
__device__ __forceinline__ int lds_swz(int r, int ck) {
    int W = ((r & 15) << 6) | (ck << 4);
    W ^= ((W >> 7) & 7) << 4;
    return ((r >> 4) << 9) + (W >> 1);
}

// ---------------- f32 -> bf16 convert (x) ----------------
__global__ __launch_bounds__(256) void cvt_bf16(const float* __restrict__ in,
                                                __bf16* __restrict__ out, int n4) {
    int i = blockIdx.x * 256 + threadIdx.x;
    if (i >= n4) return;
    f32x4 v = *(const f32x4*)(in + (size_t)i * 4);
    bf16x4 o;
#pragma unroll
    for (int j = 0; j < 4; j++) o[j] = (__bf16)v[j];
    *(bf16x4*)(out + (size_t)i * 4) = o;
}

// ---------------- weight transpose f32 (R,C) -> bf16 (C,R) ----------------
__global__ __launch_bounds__(256) void transpose_w(const float* __restrict__ in,
                                                   __bf16* __restrict__ out, int R, int C) {
    __shared__ float tile[32][33];
    const int c0 = blockIdx.x * 32, r0 = blockIdx.y * 32;
    const int tx = threadIdx.x, ty = threadIdx.y;
#pragma unroll
    for (int k = 0; k < 32; k += 8)
        tile[ty + k][tx] = in[(size_t)(r0 + ty + k) * C + c0 + tx];
    __syncthreads();
#pragma unroll
    for (int k = 0; k < 32; k += 8)
        out[(size_t)(c0 + ty + k) * R + r0 + tx] = (__bf16)tile[tx][ty + k];
}

// ---------------- GEMM: C(M,N) = A(M,K)bf16 @ Bt(N,K)bf16^T ----------------
// 128x128 tile, 4 waves. 2-buffer LDS (32KB -> 5 blocks/CU), post-barrier stage,
// counted vmcnt(4), raw s_barrier, XOR-swizzled tiles.
// Per-iter: barrier; STAGE(t+1 -> buf^(t+1)); vmcnt(4); ds_read+MFMA(buf t); lgkm(0).
// Safety: every wave's lgkm(0) precedes its barrier, so all reads of the buffer being
// overwritten are drained chip-wide before any post-barrier STAGE touches it.
template <typename OUT_T>
__global__ __launch_bounds__(256) void gemm_bt(const __bf16* __restrict__ A,
                                               const __bf16* __restrict__ Bt,
                                               OUT_T* __restrict__ C, int M, int N, int K) {
    __shared__ alignas(16) __bf16 As[2][4096];
    __shared__ alignas(16) __bf16 Bs[2][4096];
    const int tid = threadIdx.x;
    const int wv = tid >> 6;
    const int l = tid & 63;
    const int nwg = gridDim.x;
    const int cpx = nwg >> 3;
    const int bid = blockIdx.x;
    const int wg = (bid & 7) * cpx + (bid >> 3);  // XCD swizzle (nwg % 8 == 0)
    const int nbn = N >> 7;
    const int bm = wg / nbn, bn = wg - bm * nbn;

    const __bf16* Ab = A + (size_t)bm * 128 * K;
    const __bf16* Bb = Bt + (size_t)bn * 128 * K;
    // pre-swizzled global source for the linear global_load_lds dest (slot byte = l*16)
    const int L = (l << 4) ^ ((l >> 3) << 4);
    const int sr = L >> 6;               // swizzled row-in-region 0..15
    const int sc8 = ((L >> 4) & 3) * 8;  // swizzled 16B-chunk -> element offset
    const int lr = tid & 15;
    const int ck = (tid >> 4) & 3;
    const int wm = (wv >> 1) * 64, wn = (wv & 1) * 64;

    auto STAGE = [&](int buf, int kt) {
        gload_lds16(Ab + (size_t)(wv * 16 + sr) * K + kt + sc8, &As[buf][0] + wv * 512);
        gload_lds16(Ab + (size_t)(64 + wv * 16 + sr) * K + kt + sc8, &As[buf][0] + 2048 + wv * 512);
        gload_lds16(Bb + (size_t)(wv * 16 + sr) * K + kt + sc8, &Bs[buf][0] + wv * 512);
        gload_lds16(Bb + (size_t)(64 + wv * 16 + sr) * K + kt + sc8, &Bs[buf][0] + 2048 + wv * 512);
    };

    const int nt = K >> 5;  // K-tiles of 32
    STAGE(0, 0);

    f32x4 acc[4][4] = {};
    for (int t = 0; t < nt; ++t) {
        __builtin_amdgcn_s_barrier();
        __builtin_amdgcn_sched_barrier(0);
        if (t + 1 < nt) {
            STAGE((t + 1) & 1, (t + 1) * 32);
            asm volatile("s_waitcnt vmcnt(4)" ::: "memory");  // tile t landed; t+1 in flight
        } else {
            asm volatile("s_waitcnt vmcnt(0)" ::: "memory");  // tail drain
        }
        __builtin_amdgcn_sched_barrier(0);
        const __bf16* as = &As[t & 1][0];
        const __bf16* bs = &Bs[t & 1][0];
        bf16x8 af[4], bfr[4];
#pragma unroll
        for (int i = 0; i < 4; i++) af[i] = *(const bf16x8*)(as + lds_swz(wm + i * 16 + lr, ck));
#pragma unroll
        for (int j = 0; j < 4; j++) bfr[j] = *(const bf16x8*)(bs + lds_swz(wn + j * 16 + lr, ck));
#pragma unroll
        for (int i = 0; i < 4; i++)
#pragma unroll
            for (int j = 0; j < 4; j++) acc[i][j] = MFMA16(af[i], bfr[j], acc[i][j]);
        asm volatile("s_waitcnt lgkmcnt(0)" ::: "memory");  // own reads drained before next barrier
    }
    const int lro = ((tid >> 4) & 3) * 4;
#pragma unroll
    for (int i = 0; i < 4; i++)
#pragma unroll
        for (int j = 0; j < 4; j++) {
            size_t base = (size_t)(bm * 128 + wm + i * 16 + lro) * N + bn * 128 + wn + j * 16 + lr;
#pragma unroll
            for (int r = 0; r < 4; r++) C[base + (size_t)r * N] = (OUT_T)acc[i][j][r];
        }
}

// ---------------- t = x @ gk_w1  (8192x16) ----------------
__global__ __launch_bounds__(256) void gk1_proj(const float* __restrict__ x,
                                                const float* __restrict__ w1,
                                                float* __restrict__ t) {
    const int row = blockIdx.x * 4 + (threadIdx.x >> 6);
    const int l = threadIdx.x & 63;
    const int r = l & 15, kg = l >> 4;
    const float* xr = x + (size_t)row * 1024;
    const float* w1p = w1 + r;
    float acc = 0.f;
    for (int k = kg * 256; k < (kg + 1) * 256; ++k) acc = fmaf(xr[k], w1p[k * 16], acc);
    acc += __shfl_xor(acc, 16);
    acc += __shfl_xor(acc, 32);
    if (kg == 0) t[(size_t)row * 16 + r] = acc;
}

// ---------------- per-(b,h,chunk128): gates, qg, kg, kgT, e^blast ----------------
// block 1024 = 4 c-quarters x 256 d. Serial chain is 32 (not 128); quarter prefix via LDS.
__global__ __launch_bounds__(1024, 4) void gate_qkg(
    const float* __restrict__ tbuf,   // (8192,16)
    const float* __restrict__ w2,     // (16,1024)
    const float* __restrict__ b2,     // (1024)
    const __bf16* __restrict__ qkbuf, // (8192,2048): q|k
    __bf16* __restrict__ qg,          // (8192,1024)
    __bf16* __restrict__ kg,          // (8192,1024)
    __bf16* __restrict__ kgT,         // (16,256,2048) [bh][d][seq]
    float* __restrict__ ebl)          // (16,16,256) [nc][bh][d]
{
    __shared__ alignas(16) float t_l[128 * 16];  // 8KB
    __shared__ float qs[4 * 256];                // 4KB quarter totals
    __shared__ __bf16 kg_l[128 * 260];           // 66.5KB
    const int bid = blockIdx.x;
    const int bh = bid & 15, nc = bid >> 4;
    const int b = bh >> 2, h = bh & 3;
    const int tid = threadIdx.x;
    const int d = tid & 255, cq = tid >> 8;
    const int seq0 = b * 2048 + nc * 128;
    const int hd = h * 256 + d;

    for (int i = tid; i < 128 * 16; i += 1024) t_l[i] = tbuf[(size_t)seq0 * 16 + i];
    float w2c[16];
#pragma unroll
    for (int r = 0; r < 16; r++) w2c[r] = w2[r * 1024 + hd];
    const float b2v = b2[hd];
    __syncthreads();

    // phase B: within-quarter inclusive cumsum of log-sigmoid gates (registers, unrolled)
    float bs[32];
    float run = 0.f;
#pragma unroll
    for (int j = 0; j < 32; j++) {
        const int c = cq * 32 + j;
        f32x4 t0 = *(const f32x4*)(t_l + c * 16);
        f32x4 t1 = *(const f32x4*)(t_l + c * 16 + 4);
        f32x4 t2 = *(const f32x4*)(t_l + c * 16 + 8);
        f32x4 t3 = *(const f32x4*)(t_l + c * 16 + 12);
        float u = b2v;
#pragma unroll
        for (int r = 0; r < 4; r++) {
            u = fmaf(t0[r], w2c[r], u);
            u = fmaf(t1[r], w2c[4 + r], u);
            u = fmaf(t2[r], w2c[8 + r], u);
            u = fmaf(t3[r], w2c[12 + r], u);
        }
        const float ls = fminf(u, 0.f) - __logf(1.f + __expf(-fabsf(u)));
        run += ls * 0.0625f;  // / GATE_NORM
        bs[j] = run;
    }
    qs[cq * 256 + d] = run;
    __syncthreads();

    float prefix = 0.f;
#pragma unroll
    for (int q = 0; q < 3; q++)
        if (q < cq) prefix += qs[q * 256 + d];

    // phase C: apply gates to q/k, write qg/kg, stage kg for transpose
#pragma unroll
    for (int j = 0; j < 32; j++) {
        const int c = cq * 32 + j;
        const float bsum = prefix + bs[j];
        const float eb = __expf(bsum);
        const float en = __expf(-bsum);
        const float qv = (float)qkbuf[(size_t)(seq0 + c) * 2048 + hd];
        const float kv = (float)qkbuf[(size_t)(seq0 + c) * 2048 + 1024 + hd];
        qg[(size_t)(seq0 + c) * 1024 + hd] = (__bf16)(qv * eb * 0.0625f);
        const __bf16 kgv = (__bf16)(kv * en);
        kg[(size_t)(seq0 + c) * 1024 + hd] = kgv;
        kg_l[c * 260 + d] = kgv;
    }
    if (cq == 3) ebl[(size_t)(nc * 16 + bh) * 256 + d] = __expf(prefix + bs[31]);
    __syncthreads();

    // phase D: transpose kg -> kgT (seq-contiguous rows per d); 1024 threads, 32 iters each
    {
        const int cc = tid & 127, dgroup = tid >> 7;  // 8 groups of 32 d
        for (int i = 0; i < 32; i++) {
            const int dd = dgroup * 32 + i;
            kgT[(size_t)(bh * 256 + dd) * 2048 + nc * 128 + cc] = kg_l[cc * 260 + dd];
        }
    }
}

// ---------------- a_mat: A = causal(qg kg^T), materialized (256 pairs) ----------------
// grid 256 = pair (nc*16+bh), block 512 (8 waves).
// A is 128x128: 8x8 grid of 16x16 blocks; 36 lower-triangle blocks dealt round-robin to 8 waves.
__global__ __launch_bounds__(512) void a_mat(
    const __bf16* __restrict__ qg, const __bf16* __restrict__ kg,
    __bf16* __restrict__ Abuf) {
    const int pair = blockIdx.x;
    const int bh = pair & 15, nc = pair >> 4;
    const int b = bh >> 2, h = bh & 3;
    const int tid = threadIdx.x, wv = tid >> 6, l = tid & 63;
    const int lr = l & 15, lk = (l >> 4) * 8, lro = (l >> 4) * 4;
    const int seq0 = b * 2048 + nc * 128;
    __bf16* Ab = Abuf + (size_t)pair * 16384;

    // phase 1: zero the whole 128x128 tile
    {
        bf16x8 z = {};
        for (int i = tid; i < 2048; i += 512) *(bf16x8*)(Ab + (size_t)i * 8) = z;
    }
    __syncthreads();

    // phase 2: compute lower-triangle 16x16 blocks (j = t-strip, s = s-strip, s <= j)
    static const int TJ[36] = {0,1,1,2,2,2,3,3,3,3,4,4,4,4,4,5,5,5,5,5,5,
                               6,6,6,6,6,6,6,7,7,7,7,7,7,7,7};
    static const int TS[36] = {0,0,1,0,1,2,0,1,2,3,0,1,2,3,4,0,1,2,3,4,5,
                               0,1,2,3,4,5,6,0,1,2,3,4,5,6,7};
    for (int m = wv; m < 36; m += 8) {
        const int j = TJ[m], s = TS[m];
        f32x4 acc = {};
        const __bf16* qrow = qg + (size_t)(seq0 + j * 16 + lr) * 1024 + h * 256;
        const __bf16* krow = kg + (size_t)(seq0 + s * 16 + lr) * 1024 + h * 256;
#pragma unroll
        for (int ks = 0; ks < 8; ks++) {
            bf16x8 a = *(const bf16x8*)(qrow + ks * 32 + lk);
            bf16x8 bb = *(const bf16x8*)(krow + ks * 32 + lk);
            acc = MFMA16(a, bb, acc);
        }
#pragma unroll
        for (int r = 0; r < 4; r++) {
            const int t = j * 16 + lro + r;
            const int ss = s * 16 + lr;
            if (ss <= t) Ab[t * 128 + ss] = (__bf16)acc[r];
        }
    }
}

// ---------------- ointer: o = [A|qg] @ [vt_slice | H_slot]^T ----------------
// grid 1024 = pair(256) x bn(4), block 256. K = 384 (128 s + 256 d); nc==0 -> K=128.
// Same 2-buffer post-barrier-stage pipeline as gemm_bt.
__global__ __launch_bounds__(256) void ointer(
    const __bf16* __restrict__ Abuf, const __bf16* __restrict__ qg,
    const __bf16* __restrict__ vt, const __bf16* __restrict__ UH,
    __bf16* __restrict__ ob) {
    __shared__ alignas(16) __bf16 As[2][4096];
    __shared__ alignas(16) __bf16 Bs[2][4096];
    const int tid = threadIdx.x;
    const int wv = tid >> 6;
    const int l = tid & 63;
    const int bid = blockIdx.x;
    const int wg = (bid & 7) * 128 + (bid >> 3);  // XCD swizzle, 1024 blocks
    const int bn = wg & 3, pair = wg >> 2;        // consecutive wg share pair -> L2 reuse of A/qg
    const int bh = pair & 15, nc = pair >> 4;
    const int b = bh >> 2, h = bh & 3;
    const int seq0 = b * 2048 + nc * 128;
    const int L = (l << 4) ^ ((l >> 3) << 4);
    const int sr = L >> 6;
    const int sc8 = ((L >> 4) & 3) * 8;
    const int lr = tid & 15;
    const int ck = (tid >> 4) & 3;
    const int wm = (wv >> 1) * 64, wn = (wv & 1) * 64;
    const int KE = (nc == 0) ? 128 : 384;

    const __bf16* Ap = Abuf + (size_t)pair * 16384;
    const __bf16* Hb = UH + ((size_t)((nc - 1) * 16 + bh) * 512 + bn * 128) * 256;

    auto STAGE = [&](int buf, int kt) {
        const __bf16 *a0, *a1, *b0, *b1;
        if (kt < 128) {
            a0 = Ap + (size_t)(wv * 16 + sr) * 128 + kt + sc8;
            a1 = Ap + (size_t)(64 + wv * 16 + sr) * 128 + kt + sc8;
            b0 = vt + (size_t)(h * 512 + bn * 128 + wv * 16 + sr) * 8192 + seq0 + kt + sc8;
            b1 = vt + (size_t)(h * 512 + bn * 128 + 64 + wv * 16 + sr) * 8192 + seq0 + kt + sc8;
        } else {
            const int kd = kt - 128;
            a0 = qg + (size_t)(seq0 + wv * 16 + sr) * 1024 + h * 256 + kd + sc8;
            a1 = qg + (size_t)(seq0 + 64 + wv * 16 + sr) * 1024 + h * 256 + kd + sc8;
            b0 = Hb + (size_t)(wv * 16 + sr) * 256 + kd + sc8;
            b1 = Hb + (size_t)(64 + wv * 16 + sr) * 256 + kd + sc8;
        }
        gload_lds16(a0, &As[buf][0] + wv * 512);
        gload_lds16(a1, &As[buf][0] + 2048 + wv * 512);
        gload_lds16(b0, &Bs[buf][0] + wv * 512);
        gload_lds16(b1, &Bs[buf][0] + 2048 + wv * 512);
    };

    const int nt = KE >> 5;  // 4 or 12
    STAGE(0, 0);

    f32x4 acc[4][4] = {};
    for (int t = 0; t < nt; ++t) {
        __builtin_amdgcn_s_barrier();
        __builtin_amdgcn_sched_barrier(0);
        if (t + 1 < nt) {
            STAGE((t + 1) & 1, (t + 1) * 32);
            asm volatile("s_waitcnt vmcnt(4)" ::: "memory");
        } else {
            asm volatile("s_waitcnt vmcnt(0)" ::: "memory");
        }
        __builtin_amdgcn_sched_barrier(0);
        const __bf16* as = &As[t & 1][0];
        const __bf16* bs = &Bs[t & 1][0];
        bf16x8 af[4], bfr[4];
#pragma unroll
        for (int i = 0; i < 4; i++) af[i] = *(const bf16x8*)(as + lds_swz(wm + i * 16 + lr, ck));
#pragma unroll
        for (int j = 0; j < 4; j++) bfr[j] = *(const bf16x8*)(bs + lds_swz(wn + j * 16 + lr, ck));
#pragma unroll
        for (int i = 0; i < 4; i++)
#pragma unroll
            for (int j = 0; j < 4; j++) acc[i][j] = MFMA16(af[i], bfr[j], acc[i][j]);
        asm volatile("s_waitcnt lgkmcnt(0)" ::: "memory");
    }
    const int lro = ((tid >> 4) & 3) * 4;
#pragma unroll
    for (int i = 0; i < 4; i++)
#pragma unroll
        for (int j = 0; j < 4; j++) {
            size_t base = (size_t)(seq0 + wm + i * 16 + lro) * 2048 + h * 512 + bn * 128 + wn + j * 16 + lr;
#pragma unroll
            for (int r = 0; r < 4; r++) ob[base + (size_t)r * 2048] = (__bf16)acc[i][j][r];
        }
}

// ---------------- chunk_u: Ut_i[e][d] = sum_c vt[e][c] * kgT[d][c]  (parallel over all chunks) ----
// grid 1024 = q(4: eh*2+dh) x nc(16) x bh(16), block 512 (8 waves: 4 e-frags x 2 d-frags)
__global__ __launch_bounds__(512) void chunk_u(
    const __bf16* __restrict__ vt, const __bf16* __restrict__ kgT,
    __bf16* __restrict__ UH) {
    const int bid = blockIdx.x;
    const int bh = bid & 15, nc = (bid >> 4) & 15, q = bid >> 8;
    const int eh = q >> 1, dh = q & 1;
    const int b = bh >> 2, h = bh & 3;
    const int tid = threadIdx.x, wv = tid >> 6, l = tid & 63;
    const int lr = l & 15, lk = (l >> 4) * 8, lro = (l >> 4) * 4;
    const int seq0 = b * 2048 + nc * 128;
    const int e0 = eh * 256 + (wv >> 1) * 64;  // within [0,512)
    const int d0 = dh * 128 + (wv & 1) * 64;   // within [0,256)
    const __bf16* va = vt + (size_t)(h * 512 + e0) * 8192 + seq0;
    const __bf16* kb = kgT + (size_t)(bh * 256 + d0) * 2048 + nc * 128;

    f32x4 acc[4][4] = {};
#pragma unroll
    for (int ks = 0; ks < 4; ks++) {
        bf16x8 af[4], bf_[4];
#pragma unroll
        for (int i = 0; i < 4; i++)
            af[i] = *(const bf16x8*)(va + (size_t)(i * 16 + lr) * 8192 + ks * 32 + lk);
#pragma unroll
        for (int j = 0; j < 4; j++)
            bf_[j] = *(const bf16x8*)(kb + (size_t)(j * 16 + lr) * 2048 + ks * 32 + lk);
#pragma unroll
        for (int i = 0; i < 4; i++)
#pragma unroll
            for (int j = 0; j < 4; j++) acc[i][j] = MFMA16(af[i], bf_[j], acc[i][j]);
    }
    __bf16* ub = UH + ((size_t)(nc * 16 + bh) * 512 + e0) * 256 + d0;
#pragma unroll
    for (int i = 0; i < 4; i++)
#pragma unroll
        for (int j = 0; j < 4; j++)
#pragma unroll
            for (int r = 0; r < 4; r++)
                ub[(size_t)(i * 16 + lro + r) * 256 + j * 16 + lr] = (__bf16)acc[i][j][r];
}

// ---------------- hscan: in-place elementwise scan over 16 chunk slots ----------------
// slot i holds Ut_i on entry; on exit holds H_{i+1} = E_i (H_i + Ut_i).  H in f32 regs.
__global__ __launch_bounds__(256) void hscan(__bf16* __restrict__ UH,
                                             const float* __restrict__ ebl) {
    const int t = blockIdx.x * 256 + threadIdx.x;  // 262144 threads
    const int bh = t >> 14;
    const int rem = t & 16383;
    const int e = rem >> 5, d0 = (rem & 31) * 8;
    float H[8];
#pragma unroll
    for (int j = 0; j < 8; j++) H[j] = 0.f;
    for (int i = 0; i < 16; i++) {
        size_t idx = ((size_t)(i * 16 + bh) * 512 + e) * 256 + d0;
        bf16x8 u = *(const bf16x8*)(UH + idx);
        const float* ep = ebl + (size_t)(i * 16 + bh) * 256 + d0;
        f32x4 e0v = *(const f32x4*)ep;
        f32x4 e1v = *(const f32x4*)(ep + 4);
        bf16x8 hw;
#pragma unroll
        for (int j = 0; j < 4; j++) {
            H[j] = e0v[j] * (H[j] + (float)u[j]);
            hw[j] = (__bf16)H[j];
        }
#pragma unroll
        for (int j = 4; j < 8; j++) {
            H[j] = e1v[j - 4] * (H[j] + (float)u[j]);
            hw[j] = (__bf16)H[j];
        }
        *(bf16x8*)(UH + idx) = hw;
    }
}

// ---------------- RMS norm over dv=512 + SiLU gating ----------------
__global__ __launch_bounds__(256) void rms_gate(const __bf16* __restrict__ ob,
                                                const __bf16* __restrict__ gbuf,
                                                const float* __restrict__ gnw,
                                                __bf16* __restrict__ gated) {
    const int idx = blockIdx.x * 4 + (threadIdx.x >> 6);
    const int seq = idx >> 2, h = idx & 3;
    const int l = threadIdx.x & 63;
    bf16x8 o1 = *(const bf16x8*)(ob + (size_t)seq * 2048 + h * 512 + l * 8);
    float v[8];
    float ms = 0.f;
#pragma unroll
    for (int j = 0; j < 8; j++) {
        v[j] = (float)o1[j];
        ms += v[j] * v[j];
    }
#pragma unroll
    for (int off = 1; off < 64; off <<= 1) ms += __shfl_xor(ms, off);
    const float rinv = rsqrtf(ms * (1.f / 512.f) + 1e-5f);
    bf16x8 gv = *(const bf16x8*)(gbuf + (size_t)seq * 2048 + h * 512 + l * 8);
    const float* gw = gnw + l * 8;
    bf16x8 outv;
#pragma unroll
    for (int j = 0; j < 8; j++) {
        float g = (float)gv[j];
        float sig = 1.f / (1.f + expf(-g));
        outv[j] = (__bf16)(v[j] * rinv * gw[j] * g * sig);
    }
    *(bf16x8*)(gated + (size_t)seq * 2048 + h * 512 + l * 8) = outv;
}

extern "C" void kernel_launch(void* const* d_in, const int* in_sizes, int n_in,
                              void* d_out, int out_size, void* d_ws, size_t ws_size,
                              hipStream_t stream) {
    const float* x = (const float*)d_in[0];
    const float* Wq = (const float*)d_in[1];
    const float* Wk = (const float*)d_in[2];
    const float* Wv = (const float*)d_in[3];
    const float* Wg = (const float*)d_in[4];
    const float* w1 = (const float*)d_in[5];
    const float* w2 = (const float*)d_in[6];
    const float* b2 = (const float*)d_in[7];
    const float* gnw = (const float*)d_in[8];
    const float* Wo = (const float*)d_in[9];
    float* out = (float*)d_out;

    char* p = (char*)d_ws;
    auto nxt = [&](size_t bytes) {
        char* r = p;
        p += (bytes + 255) & ~(size_t)255;
        return r;
    };
    __bf16* xb = (__bf16*)nxt(8192ull * 1024 * 2);    // dead after vt GEMM -> kg aliases
    __bf16* WTqk = (__bf16*)nxt(2048ull * 1024 * 2);  // WqT | WkT; dead after proj -> Abuf aliases
    __bf16* WTg = (__bf16*)nxt(2048ull * 1024 * 2);   // dead after proj -> Abuf aliases
    __bf16* WvT = (__bf16*)nxt(2048ull * 1024 * 2);   // dead after proj
    __bf16* WoT = (__bf16*)nxt(1024ull * 2048 * 2);   // live until final GEMM
    __bf16* gbuf = (__bf16*)nxt(8192ull * 2048 * 2);
    __bf16* vt = (__bf16*)nxt(2048ull * 8192 * 2);
    float* tbuf = (float*)nxt(8192ull * 16 * 4);
    __bf16* qg = (__bf16*)nxt(8192ull * 1024 * 2);
    __bf16* kgT = (__bf16*)nxt(16ull * 256 * 2048 * 2);
    float* ebl = (float*)nxt(16ull * 16 * 256 * 4);
    __bf16* ob = (__bf16*)nxt(8192ull * 2048 * 2);
    __bf16* UH = (__bf16*)nxt(16ull * 16 * 512 * 256 * 2);  // 64MB: Ut slots -> H states (in-place)
    __bf16* kg = xb;        // alias: xb dead before gate_qkg writes kg
    __bf16* qkbuf = UH;     // alias: q|k projection; dead (read by gate_qkg) before chunk_u writes UH
    __bf16* gated = UH;     // alias: UH dead (read by ointer) before rms_gate writes gated
    __bf16* Abuf = WTqk;    // alias: 8MB = WTqk+WTg exactly, both dead before a_mat

    dim3 tb(32, 8);
    cvt_bf16<<<8192, 256, 0, stream>>>(x, xb, 2097152);
    transpose_w<<<dim3(32, 32), tb, 0, stream>>>(Wq, WTqk, 1024, 1024);
    transpose_w<<<dim3(32, 32), tb, 0, stream>>>(Wk, WTqk + 1024 * 1024, 1024, 1024);
    transpose_w<<<dim3(64, 32), tb, 0, stream>>>(Wg, WTg, 1024, 2048);
    transpose_w<<<dim3(64, 32), tb, 0, stream>>>(Wv, WvT, 1024, 2048);
    transpose_w<<<dim3(32, 64), tb, 0, stream>>>(Wo, WoT, 2048, 1024);
    gk1_proj<<<2048, 256, 0, stream>>>(x, w1, tbuf);
    gemm_bt<__bf16><<<1024, 256, 0, stream>>>(xb, WTqk, qkbuf, 8192, 2048, 1024);
    gemm_bt<__bf16><<<1024, 256, 0, stream>>>(xb, WTg, gbuf, 8192, 2048, 1024);
    gemm_bt<__bf16><<<1024, 256, 0, stream>>>(WvT, xb, vt, 2048, 8192, 1024);
    gate_qkg<<<256, 1024, 0, stream>>>(tbuf, w2, b2, qkbuf, qg, kg, kgT, ebl);
    a_mat<<<256, 512, 0, stream>>>(qg, kg, Abuf);
    chunk_u<<<1024, 512, 0, stream>>>(vt, kgT, UH);
    hscan<<<1024, 256, 0, stream>>>(UH, ebl);
    ointer<<<1024, 256, 0, stream>>>(Abuf, qg, vt, UH, ob);
    rms_gate<<<8192, 256, 0, stream>>>(ob, gbuf, gnw, gated);
    gemm_bt<float><<<512, 256, 0, stream>>>(gated, WoT, out, 8192, 1024, 2048);
}